// Round 12
// baseline (202.346 us; speedup 1.0000x reference)
//
#include <hip/hip_runtime.h>

#define D 64

typedef int i32x4 __attribute__((ext_vector_type(4)));

__device__ __forceinline__ int4 nt_load_i4(const int4* p) {
    i32x4 v = __builtin_nontemporal_load(reinterpret_cast<const i32x4*>(p));
    return make_int4(v.x, v.y, v.z, v.w);
}

__global__ void k_zero4(float4* __restrict__ p, int n4) {
    int i = blockIdx.x * 256 + threadIdx.x;
    if (i < n4) p[i] = make_float4(0.f, 0.f, 0.f, 0.f);
}

// 8-way split counters: copy c = blockIdx&7. Cuts the same-address
// atomic-return dependency chain (the k_deg latency driver) by 8x.
__global__ void k_deg(const int* __restrict__ dst, int* __restrict__ cnt8,
                      int* __restrict__ rank, int N, int E) {
    int e = blockIdx.x * 256 + threadIdx.x;
    if (e < E) rank[e] = atomicAdd(&cnt8[(size_t)(blockIdx.x & 7) * N + dst[e]], 1);
}

// Scans operate on PADDED totals ((sum+7)&~7) so every CSR list is a multiple of 8.
__global__ void k_scan1(const int* __restrict__ cnt8, int* __restrict__ part, int N) {
    __shared__ int s[256];
    int t = threadIdx.x;
    int i = blockIdx.x * 256 + t;
    int v = 0;
    if (i < N) {
        #pragma unroll
        for (int c = 0; c < 8; ++c) v += cnt8[(size_t)c * N + i];
    }
    s[t] = (v + 7) & ~7;
    __syncthreads();
    for (int d = 128; d > 0; d >>= 1) {
        if (t < d) s[t] += s[t + d];
        __syncthreads();
    }
    if (t == 0) part[blockIdx.x] = s[0];
}

// scan3 with scan2 inlined: every block redundantly prefix-sums the 196 block
// partials in LDS (cheap) -> one fewer kernel launch.
__global__ void k_scan3(const int* __restrict__ cnt8, const int* __restrict__ part,
                        int* __restrict__ rp, int* __restrict__ off8,
                        float* __restrict__ dinv, int N, int nb) {
    __shared__ int s[256];
    __shared__ int sp[256];
    int t = threadIdx.x;
    int i = blockIdx.x * 256 + t;

    sp[t] = (t < nb) ? part[t] : 0;
    __syncthreads();
    for (int d = 1; d < 256; d <<= 1) {
        int add = (t >= d) ? sp[t - d] : 0;
        __syncthreads();
        sp[t] += add;
        __syncthreads();
    }
    int boff = (blockIdx.x == 0) ? 0 : sp[blockIdx.x - 1];

    int vc[8];
    int v = 0;
    if (i < N) {
        #pragma unroll
        for (int c = 0; c < 8; ++c) { vc[c] = cnt8[(size_t)c * N + i]; v += vc[c]; }
    }
    int pv = (v + 7) & ~7;
    s[t] = pv;
    __syncthreads();
    for (int d = 1; d < 256; d <<= 1) {
        int add = (t >= d) ? s[t - d] : 0;
        __syncthreads();
        s[t] += add;
        __syncthreads();
    }
    if (i < N) {
        int excl = boff + s[t] - pv;
        rp[i] = excl;
        dinv[i] = 1.0f / sqrtf((float)v + 1.0f);  // deg includes self-loop (+1)
        int run = excl;
        #pragma unroll
        for (int c = 0; c < 8; ++c) { off8[(size_t)c * N + i] = run; run += vc[c]; }
        if (i == N - 1) rp[N] = excl + pv;
    }
}

// Atomic-free scatter; 8B payload (src, dinv[src]) so k_fused has no dinv gather.
__global__ void k_fill(const int* __restrict__ src, const int* __restrict__ dst,
                       const int* __restrict__ rank, const int* __restrict__ off8,
                       const float* __restrict__ dinv, int2* __restrict__ pack,
                       int N, int E) {
    int e = blockIdx.x * 256 + threadIdx.x;
    if (e < E) {
        int s = src[e];
        int2 p;
        p.x = s;
        p.y = __float_as_int(dinv[s]);
        pack[off8[(size_t)(blockIdx.x & 7) * N + dst[e]] + rank[e]] = p;
    }
}

// Per-wave aggregation: 4 nodes/wave, float4/lane (16 lanes x 16B = one 256B row
// per group). Lists padded to x8 (dummy src=0,w=0 -> exact no-op); next pack batch
// (4x int4, NONTEMPORAL: single-touch stream, keep x rows in L2) prefetched while
// this batch's 8 row-gathers are in flight.
__device__ __forceinline__ float4 agg_row(const float4* __restrict__ x4,
                                          const int4* __restrict__ pk,
                                          int s0, int s1, float dn, int n, int l16) {
    float4 sv = x4[(size_t)n * 16 + l16];
    float dnn = dn * dn;
    float ax = sv.x * dnn, ay = sv.y * dnn, az = sv.z * dnn, aw = sv.w * dnn;
    float bx = 0.f, by = 0.f, bz = 0.f, bw = 0.f;
    int e = s0;
    int4 q0, q1, q2, q3;
    if (e < s1) {
        int h = e >> 1;
        q0 = nt_load_i4(&pk[h + 0]); q1 = nt_load_i4(&pk[h + 1]);
        q2 = nt_load_i4(&pk[h + 2]); q3 = nt_load_i4(&pk[h + 3]);
    }
    while (e < s1) {
        float4 v0 = x4[(size_t)q0.x * 16 + l16];
        float4 v1 = x4[(size_t)q0.z * 16 + l16];
        float4 v2 = x4[(size_t)q1.x * 16 + l16];
        float4 v3 = x4[(size_t)q1.z * 16 + l16];
        float4 v4 = x4[(size_t)q2.x * 16 + l16];
        float4 v5 = x4[(size_t)q2.z * 16 + l16];
        float4 v6 = x4[(size_t)q3.x * 16 + l16];
        float4 v7 = x4[(size_t)q3.z * 16 + l16];
        float c0 = __int_as_float(q0.y) * dn, c1 = __int_as_float(q0.w) * dn;
        float c2 = __int_as_float(q1.y) * dn, c3 = __int_as_float(q1.w) * dn;
        float c4 = __int_as_float(q2.y) * dn, c5 = __int_as_float(q2.w) * dn;
        float c6 = __int_as_float(q3.y) * dn, c7 = __int_as_float(q3.w) * dn;
        e += 8;
        if (e < s1) {  // prefetch next batch while gathers are in flight
            int h = e >> 1;
            q0 = nt_load_i4(&pk[h + 0]); q1 = nt_load_i4(&pk[h + 1]);
            q2 = nt_load_i4(&pk[h + 2]); q3 = nt_load_i4(&pk[h + 3]);
        }
        ax = fmaf(v0.x, c0, ax); ay = fmaf(v0.y, c0, ay); az = fmaf(v0.z, c0, az); aw = fmaf(v0.w, c0, aw);
        bx = fmaf(v1.x, c1, bx); by = fmaf(v1.y, c1, by); bz = fmaf(v1.z, c1, bz); bw = fmaf(v1.w, c1, bw);
        ax = fmaf(v2.x, c2, ax); ay = fmaf(v2.y, c2, ay); az = fmaf(v2.z, c2, az); aw = fmaf(v2.w, c2, aw);
        bx = fmaf(v3.x, c3, bx); by = fmaf(v3.y, c3, by); bz = fmaf(v3.z, c3, bz); bw = fmaf(v3.w, c3, bw);
        ax = fmaf(v4.x, c4, ax); ay = fmaf(v4.y, c4, ay); az = fmaf(v4.z, c4, az); aw = fmaf(v4.w, c4, aw);
        bx = fmaf(v5.x, c5, bx); by = fmaf(v5.y, c5, by); bz = fmaf(v5.z, c5, bz); bw = fmaf(v5.w, c5, bw);
        ax = fmaf(v6.x, c6, ax); ay = fmaf(v6.y, c6, ay); az = fmaf(v6.z, c6, az); aw = fmaf(v6.w, c6, aw);
        bx = fmaf(v7.x, c7, bx); by = fmaf(v7.y, c7, by); bz = fmaf(v7.z, c7, bz); bw = fmaf(v7.w, c7, bw);
    }
    return make_float4(ax + bx, ay + by, az + bz, aw + bw);
}

// Fused aggregate + GEMM (+optional relu). Block = 512 threads = 32 nodes (4/wave).
// 512-thread blocks: W staged once per 32 nodes (half the staging traffic of 256),
// LDS = 16KB(W) + 8.7KB(zs) = 24.7KB -> 4 blocks/CU x 8 waves = 32 waves/CU (max).
template <int RELU>
__global__ __launch_bounds__(512) void k_fused(const float* __restrict__ x,
                                               const int* __restrict__ rp,
                                               const int* __restrict__ packi,
                                               const float* __restrict__ dinv,
                                               const float* __restrict__ W,
                                               const float* __restrict__ b,
                                               float* __restrict__ y, int N) {
    __shared__ float Wl[D * D];     // Wl[k*64+j] = W[k][j]
    __shared__ float zs[32][68];    // padded: rows 272B apart -> conflict-free
    int t = threadIdx.x;

    // stage W (issued before agg; completes under it, consumed after the barrier)
    #pragma unroll
    for (int r = 0; r < 2; ++r) {
        float4 wv = reinterpret_cast<const float4*>(W)[t + 512 * r];
        *reinterpret_cast<float4*>(&Wl[(t + 512 * r) * 4]) = wv;
    }

    int lane = t & 63;
    int g = lane >> 4;
    int l16 = lane & 15;
    int r_loc = (t >> 6) * 4 + g;      // local row 0..31
    int n = blockIdx.x * 32 + r_loc;
    if (n < N) {
        float4 z = agg_row(reinterpret_cast<const float4*>(x),
                           reinterpret_cast<const int4*>(packi),
                           rp[n], rp[n + 1], dinv[n], n, l16);
        *reinterpret_cast<float4*>(&zs[r_loc][l16 * 4]) = z;
    }
    __syncthreads();

    int col4 = (t & 15) * 4;
    int row = t >> 4;                  // 0..31
    int nn = blockIdx.x * 32 + row;
    if (nn < N) {
        float4 acc = make_float4(0.f, 0.f, 0.f, 0.f);
        #pragma unroll
        for (int k = 0; k < D; k += 4) {
            float4 zv = *reinterpret_cast<const float4*>(&zs[row][k]);
            float4 w0 = *reinterpret_cast<const float4*>(&Wl[(k + 0) * D + col4]);
            float4 w1 = *reinterpret_cast<const float4*>(&Wl[(k + 1) * D + col4]);
            float4 w2 = *reinterpret_cast<const float4*>(&Wl[(k + 2) * D + col4]);
            float4 w3 = *reinterpret_cast<const float4*>(&Wl[(k + 3) * D + col4]);
            acc.x = fmaf(zv.x, w0.x, acc.x); acc.y = fmaf(zv.x, w0.y, acc.y);
            acc.z = fmaf(zv.x, w0.z, acc.z); acc.w = fmaf(zv.x, w0.w, acc.w);
            acc.x = fmaf(zv.y, w1.x, acc.x); acc.y = fmaf(zv.y, w1.y, acc.y);
            acc.z = fmaf(zv.y, w1.z, acc.z); acc.w = fmaf(zv.y, w1.w, acc.w);
            acc.x = fmaf(zv.z, w2.x, acc.x); acc.y = fmaf(zv.z, w2.y, acc.y);
            acc.z = fmaf(zv.z, w2.z, acc.z); acc.w = fmaf(zv.z, w2.w, acc.w);
            acc.x = fmaf(zv.w, w3.x, acc.x); acc.y = fmaf(zv.w, w3.y, acc.y);
            acc.z = fmaf(zv.w, w3.z, acc.z); acc.w = fmaf(zv.w, w3.w, acc.w);
        }
        float4 bv = *reinterpret_cast<const float4*>(&b[col4]);
        float4 r = make_float4(acc.x + bv.x, acc.y + bv.y, acc.z + bv.z, acc.w + bv.w);
        if (RELU) {
            r.x = fmaxf(r.x, 0.f); r.y = fmaxf(r.y, 0.f);
            r.z = fmaxf(r.z, 0.f); r.w = fmaxf(r.w, 0.f);
        }
        *reinterpret_cast<float4*>(&y[(size_t)nn * D + col4]) = r;
    }
}

// Dual-output final layer: ONE 16KB W buffer staged twice (Wa -> GEMM-A ->
// barrier -> restage Wb -> GEMM-B). Same 24.7KB LDS -> 4 blocks/CU.
__global__ __launch_bounds__(512) void k_fused_dual(const float* __restrict__ x,
                                                    const int* __restrict__ rp,
                                                    const int* __restrict__ packi,
                                                    const float* __restrict__ dinv,
                                                    const float* __restrict__ Wa,
                                                    const float* __restrict__ ba,
                                                    const float* __restrict__ Wb,
                                                    const float* __restrict__ bb,
                                                    float* __restrict__ ya,
                                                    float* __restrict__ yb, int N) {
    __shared__ float Wl[D * D];
    __shared__ float zs[32][68];
    int t = threadIdx.x;

    #pragma unroll
    for (int r = 0; r < 2; ++r) {
        float4 wv = reinterpret_cast<const float4*>(Wa)[t + 512 * r];
        *reinterpret_cast<float4*>(&Wl[(t + 512 * r) * 4]) = wv;
    }

    int lane = t & 63;
    int g = lane >> 4;
    int l16 = lane & 15;
    int r_loc = (t >> 6) * 4 + g;
    int n = blockIdx.x * 32 + r_loc;
    if (n < N) {
        float4 z = agg_row(reinterpret_cast<const float4*>(x),
                           reinterpret_cast<const int4*>(packi),
                           rp[n], rp[n + 1], dinv[n], n, l16);
        *reinterpret_cast<float4*>(&zs[r_loc][l16 * 4]) = z;
    }
    __syncthreads();

    int col4 = (t & 15) * 4;
    int row = t >> 4;
    int nn = blockIdx.x * 32 + row;

    // GEMM A (mu)
    {
        float4 acc = make_float4(0.f, 0.f, 0.f, 0.f);
        #pragma unroll
        for (int k = 0; k < D; k += 4) {
            float4 zv = *reinterpret_cast<const float4*>(&zs[row][k]);
            float4 w0 = *reinterpret_cast<const float4*>(&Wl[(k + 0) * D + col4]);
            float4 w1 = *reinterpret_cast<const float4*>(&Wl[(k + 1) * D + col4]);
            float4 w2 = *reinterpret_cast<const float4*>(&Wl[(k + 2) * D + col4]);
            float4 w3 = *reinterpret_cast<const float4*>(&Wl[(k + 3) * D + col4]);
            acc.x = fmaf(zv.x, w0.x, acc.x); acc.y = fmaf(zv.x, w0.y, acc.y);
            acc.z = fmaf(zv.x, w0.z, acc.z); acc.w = fmaf(zv.x, w0.w, acc.w);
            acc.x = fmaf(zv.y, w1.x, acc.x); acc.y = fmaf(zv.y, w1.y, acc.y);
            acc.z = fmaf(zv.y, w1.z, acc.z); acc.w = fmaf(zv.y, w1.w, acc.w);
            acc.x = fmaf(zv.z, w2.x, acc.x); acc.y = fmaf(zv.z, w2.y, acc.y);
            acc.z = fmaf(zv.z, w2.z, acc.z); acc.w = fmaf(zv.z, w2.w, acc.w);
            acc.x = fmaf(zv.w, w3.x, acc.x); acc.y = fmaf(zv.w, w3.y, acc.y);
            acc.z = fmaf(zv.w, w3.z, acc.z); acc.w = fmaf(zv.w, w3.w, acc.w);
        }
        if (nn < N) {
            float4 bv = *reinterpret_cast<const float4*>(&ba[col4]);
            *reinterpret_cast<float4*>(&ya[(size_t)nn * D + col4]) =
                make_float4(acc.x + bv.x, acc.y + bv.y, acc.z + bv.z, acc.w + bv.w);
        }
    }
    __syncthreads();   // all Wl reads done before restage

    #pragma unroll
    for (int r = 0; r < 2; ++r) {
        float4 wv = reinterpret_cast<const float4*>(Wb)[t + 512 * r];
        *reinterpret_cast<float4*>(&Wl[(t + 512 * r) * 4]) = wv;
    }
    __syncthreads();

    // GEMM B (logvar)
    {
        float4 acc = make_float4(0.f, 0.f, 0.f, 0.f);
        #pragma unroll
        for (int k = 0; k < D; k += 4) {
            float4 zv = *reinterpret_cast<const float4*>(&zs[row][k]);
            float4 w0 = *reinterpret_cast<const float4*>(&Wl[(k + 0) * D + col4]);
            float4 w1 = *reinterpret_cast<const float4*>(&Wl[(k + 1) * D + col4]);
            float4 w2 = *reinterpret_cast<const float4*>(&Wl[(k + 2) * D + col4]);
            float4 w3 = *reinterpret_cast<const float4*>(&Wl[(k + 3) * D + col4]);
            acc.x = fmaf(zv.x, w0.x, acc.x); acc.y = fmaf(zv.x, w0.y, acc.y);
            acc.z = fmaf(zv.x, w0.z, acc.z); acc.w = fmaf(zv.x, w0.w, acc.w);
            acc.x = fmaf(zv.y, w1.x, acc.x); acc.y = fmaf(zv.y, w1.y, acc.y);
            acc.z = fmaf(zv.y, w1.z, acc.z); acc.w = fmaf(zv.y, w1.w, acc.w);
            acc.x = fmaf(zv.z, w2.x, acc.x); acc.y = fmaf(zv.z, w2.y, acc.y);
            acc.z = fmaf(zv.z, w2.z, acc.z); acc.w = fmaf(zv.z, w2.w, acc.w);
            acc.x = fmaf(zv.w, w3.x, acc.x); acc.y = fmaf(zv.w, w3.y, acc.y);
            acc.z = fmaf(zv.w, w3.z, acc.z); acc.w = fmaf(zv.w, w3.w, acc.w);
        }
        if (nn < N) {
            float4 bv = *reinterpret_cast<const float4*>(&bb[col4]);
            *reinterpret_cast<float4*>(&yb[(size_t)nn * D + col4]) =
                make_float4(acc.x + bv.x, acc.y + bv.y, acc.z + bv.z, acc.w + bv.w);
        }
    }
}

extern "C" void kernel_launch(void* const* d_in, const int* in_sizes, int n_in,
                              void* d_out, int out_size, void* d_ws, size_t ws_size,
                              hipStream_t stream) {
    const float* x0  = (const float*)d_in[0];
    const int*   ei  = (const int*)d_in[1];
    const float* W1  = (const float*)d_in[2];
    const float* b1  = (const float*)d_in[3];
    const float* W2  = (const float*)d_in[4];
    const float* b2  = (const float*)d_in[5];
    const float* Wsc = (const float*)d_in[6];
    const float* bs  = (const float*)d_in[7];
    const float* Wmu = (const float*)d_in[8];
    const float* bmu = (const float*)d_in[9];
    const float* Wlv = (const float*)d_in[10];
    const float* blv = (const float*)d_in[11];

    int N = in_sizes[0] / D;
    int E = in_sizes[1] / 2;
    const int* src = ei;
    const int* dst = ei + E;

    char* ws = (char*)d_ws;
    size_t off = 0;
    auto alloc = [&](size_t bytes) {
        char* p = ws + off;
        off += (bytes + 255) & ~(size_t)255;
        return p;
    };
    int*   rp   = (int*)alloc((size_t)(N + 1) * 4);
    float* dinv = (float*)alloc((size_t)N * 4);
    int NB = (N + 255) / 256;  // 196 <= 256: in-kernel partial scan is valid
    int* part = (int*)alloc((size_t)NB * 4);
    int* rank = (int*)alloc((size_t)E * 4);
    int* off8 = (int*)alloc((size_t)8 * N * 4);
    // cnt8 and pack adjacent -> one contiguous zero-fill covers both
    char* zero_base = ws + off;
    int*  cnt8 = (int*)alloc((size_t)8 * N * 4);
    int2* pack = (int2*)alloc(((size_t)E + 8 * (size_t)N) * 8);  // padded CSR (x8 lists)
    size_t zero_bytes = (size_t)((char*)(pack + E + 8 * (size_t)N) - zero_base);
    int n4 = (int)((zero_bytes + 15) / 16);
    float* h1 = (float*)alloc((size_t)N * D * 4);
    float* h2 = (float*)alloc((size_t)N * D * 4);

    float* mu = (float*)d_out;
    float* lv = (float*)d_out + (size_t)N * D;

    int EB = (E + 255) / 256;
    k_zero4<<<(n4 + 255) / 256, 256, 0, stream>>>((float4*)zero_base, n4);
    k_deg  <<<EB, 256, 0, stream>>>(dst, cnt8, rank, N, E);
    k_scan1<<<NB, 256, 0, stream>>>(cnt8, part, N);
    k_scan3<<<NB, 256, 0, stream>>>(cnt8, part, rp, off8, dinv, N, NB);
    k_fill <<<EB, 256, 0, stream>>>(src, dst, rank, off8, dinv, pack, N, E);

    int FB = (N + 31) / 32;   // 32 nodes per 512-thread block (4 per wave)
    // agg(x)@W == agg(x@W) by linearity; mu/logvar share the last aggregation.
    k_fused<0><<<FB, 512, 0, stream>>>(x0, rp, (const int*)pack, dinv, W1, b1, h1, N);
    k_fused<0><<<FB, 512, 0, stream>>>(h1, rp, (const int*)pack, dinv, W2, b2, h2, N);
    k_fused<1><<<FB, 512, 0, stream>>>(h2, rp, (const int*)pack, dinv, Wsc, bs, h1, N);
    k_fused_dual<<<FB, 512, 0, stream>>>(h1, rp, (const int*)pack, dinv,
                                         Wmu, bmu, Wlv, blv, mu, lv, N);
}

// Round 13
// 188.986 us; speedup vs baseline: 1.0707x; 1.0707x over previous
//
#include <hip/hip_runtime.h>

#define D 64

__global__ void k_zero4(float4* __restrict__ p, int n4) {
    int i = blockIdx.x * 256 + threadIdx.x;
    if (i < n4) p[i] = make_float4(0.f, 0.f, 0.f, 0.f);
}

// 8-way split counters: copy c = blockIdx&7. Cuts the same-address
// atomic-return dependency chain (the k_deg latency driver) by 8x.
__global__ void k_deg(const int* __restrict__ dst, int* __restrict__ cnt8,
                      int* __restrict__ rank, int N, int E) {
    int e = blockIdx.x * 256 + threadIdx.x;
    if (e < E) rank[e] = atomicAdd(&cnt8[(size_t)(blockIdx.x & 7) * N + dst[e]], 1);
}

// Scans operate on PADDED totals ((sum+7)&~7) so every CSR list is a multiple of 8.
__global__ void k_scan1(const int* __restrict__ cnt8, int* __restrict__ part, int N) {
    __shared__ int s[256];
    int t = threadIdx.x;
    int i = blockIdx.x * 256 + t;
    int v = 0;
    if (i < N) {
        #pragma unroll
        for (int c = 0; c < 8; ++c) v += cnt8[(size_t)c * N + i];
    }
    s[t] = (v + 7) & ~7;
    __syncthreads();
    for (int d = 128; d > 0; d >>= 1) {
        if (t < d) s[t] += s[t + d];
        __syncthreads();
    }
    if (t == 0) part[blockIdx.x] = s[0];
}

__global__ void k_scan2(const int* __restrict__ part, int* __restrict__ boff, int nb) {
    __shared__ int s[256];
    int t = threadIdx.x;
    int v = (t < nb) ? part[t] : 0;
    s[t] = v;
    __syncthreads();
    for (int d = 1; d < 256; d <<= 1) {
        int add = (t >= d) ? s[t - d] : 0;
        __syncthreads();
        s[t] += add;
        __syncthreads();
    }
    if (t < nb) boff[t] = s[t] - v;  // exclusive prefix of block partials
}

__global__ void k_scan3(const int* __restrict__ cnt8, const int* __restrict__ boff,
                        int* __restrict__ rp, int* __restrict__ off8,
                        float* __restrict__ dinv, int N) {
    __shared__ int s[256];
    int t = threadIdx.x;
    int i = blockIdx.x * 256 + t;
    int vc[8];
    int v = 0;
    if (i < N) {
        #pragma unroll
        for (int c = 0; c < 8; ++c) { vc[c] = cnt8[(size_t)c * N + i]; v += vc[c]; }
    }
    int pv = (v + 7) & ~7;
    s[t] = pv;
    __syncthreads();
    for (int d = 1; d < 256; d <<= 1) {
        int add = (t >= d) ? s[t - d] : 0;
        __syncthreads();
        s[t] += add;
        __syncthreads();
    }
    if (i < N) {
        int excl = boff[blockIdx.x] + s[t] - pv;
        rp[i] = excl;
        dinv[i] = 1.0f / sqrtf((float)v + 1.0f);  // deg includes self-loop (+1)
        int run = excl;
        #pragma unroll
        for (int c = 0; c < 8; ++c) { off8[(size_t)c * N + i] = run; run += vc[c]; }
        if (i == N - 1) rp[N] = excl + pv;
    }
}

// Atomic-free scatter; 8B payload (src, dinv[src]) so k_fused has no dinv gather.
__global__ void k_fill(const int* __restrict__ src, const int* __restrict__ dst,
                       const int* __restrict__ rank, const int* __restrict__ off8,
                       const float* __restrict__ dinv, int2* __restrict__ pack,
                       int N, int E) {
    int e = blockIdx.x * 256 + threadIdx.x;
    if (e < E) {
        int s = src[e];
        int2 p;
        p.x = s;
        p.y = __float_as_int(dinv[s]);
        pack[off8[(size_t)(blockIdx.x & 7) * N + dst[e]] + rank[e]] = p;
    }
}

// Fused aggregate + GEMM (+optional relu). Block = 256 threads = 16 nodes (4/wave).
// Phase 1 (agg): 4 nodes/wave, float4/lane; lists padded to x8 (dummy src=0,w=0 -> no-op);
//   pack batch for iter i+1 prefetched while iter i's 8 row-gathers are in flight.
// Phase 2 (gemm): z-tile (16x68 LDS, padded -> conflict-free) x W (LDS) applied in-block.
template <int RELU>
__global__ __launch_bounds__(256) void k_fused(const float* __restrict__ x,
                                               const int* __restrict__ rp,
                                               const int* __restrict__ packi,
                                               const float* __restrict__ dinv,
                                               const float* __restrict__ W,
                                               const float* __restrict__ b,
                                               float* __restrict__ y, int N) {
    __shared__ float Wl[D * D];     // Wl[k*64+j] = W[k][j]
    __shared__ float zs[16][68];    // padded: rows 272B apart -> gemm reads conflict-free
    int t = threadIdx.x;

    // stage W (completes while agg runs; consumed after the barrier)
    #pragma unroll
    for (int r = 0; r < 4; ++r) {
        float4 wv = reinterpret_cast<const float4*>(W)[t + 256 * r];
        *reinterpret_cast<float4*>(&Wl[(t + 256 * r) * 4]) = wv;
    }

    int lane = t & 63;
    int g = lane >> 4;       // node group within wave
    int l16 = lane & 15;     // owns features 4*l16..4*l16+3
    int r_loc = (t >> 6) * 4 + g;      // local row 0..15
    int n = blockIdx.x * 16 + r_loc;
    if (n < N) {
        int s0 = rp[n], s1 = rp[n + 1];   // multiples of 8
        float dn = dinv[n];
        const float4* x4 = reinterpret_cast<const float4*>(x);
        const int4* pk = reinterpret_cast<const int4*>(packi);
        float4 sv = x4[(size_t)n * 16 + l16];
        float dnn = dn * dn;
        float ax = sv.x * dnn, ay = sv.y * dnn, az = sv.z * dnn, aw = sv.w * dnn;
        float bx = 0.f, by = 0.f, bz = 0.f, bw = 0.f;
        int e = s0;
        int4 q0, q1, q2, q3;
        if (e < s1) {
            int h = e >> 1;
            q0 = pk[h]; q1 = pk[h + 1]; q2 = pk[h + 2]; q3 = pk[h + 3];
        }
        while (e < s1) {
            float4 v0 = x4[(size_t)q0.x * 16 + l16];
            float4 v1 = x4[(size_t)q0.z * 16 + l16];
            float4 v2 = x4[(size_t)q1.x * 16 + l16];
            float4 v3 = x4[(size_t)q1.z * 16 + l16];
            float4 v4 = x4[(size_t)q2.x * 16 + l16];
            float4 v5 = x4[(size_t)q2.z * 16 + l16];
            float4 v6 = x4[(size_t)q3.x * 16 + l16];
            float4 v7 = x4[(size_t)q3.z * 16 + l16];
            float c0 = __int_as_float(q0.y) * dn, c1 = __int_as_float(q0.w) * dn;
            float c2 = __int_as_float(q1.y) * dn, c3 = __int_as_float(q1.w) * dn;
            float c4 = __int_as_float(q2.y) * dn, c5 = __int_as_float(q2.w) * dn;
            float c6 = __int_as_float(q3.y) * dn, c7 = __int_as_float(q3.w) * dn;
            e += 8;
            if (e < s1) {  // prefetch next batch while gathers are in flight
                int h = e >> 1;
                q0 = pk[h]; q1 = pk[h + 1]; q2 = pk[h + 2]; q3 = pk[h + 3];
            }
            ax = fmaf(v0.x, c0, ax); ay = fmaf(v0.y, c0, ay); az = fmaf(v0.z, c0, az); aw = fmaf(v0.w, c0, aw);
            bx = fmaf(v1.x, c1, bx); by = fmaf(v1.y, c1, by); bz = fmaf(v1.z, c1, bz); bw = fmaf(v1.w, c1, bw);
            ax = fmaf(v2.x, c2, ax); ay = fmaf(v2.y, c2, ay); az = fmaf(v2.z, c2, az); aw = fmaf(v2.w, c2, aw);
            bx = fmaf(v3.x, c3, bx); by = fmaf(v3.y, c3, by); bz = fmaf(v3.z, c3, bz); bw = fmaf(v3.w, c3, bw);
            ax = fmaf(v4.x, c4, ax); ay = fmaf(v4.y, c4, ay); az = fmaf(v4.z, c4, az); aw = fmaf(v4.w, c4, aw);
            bx = fmaf(v5.x, c5, bx); by = fmaf(v5.y, c5, by); bz = fmaf(v5.z, c5, bz); bw = fmaf(v5.w, c5, bw);
            ax = fmaf(v6.x, c6, ax); ay = fmaf(v6.y, c6, ay); az = fmaf(v6.z, c6, az); aw = fmaf(v6.w, c6, aw);
            bx = fmaf(v7.x, c7, bx); by = fmaf(v7.y, c7, by); bz = fmaf(v7.z, c7, bz); bw = fmaf(v7.w, c7, bw);
        }
        *reinterpret_cast<float4*>(&zs[r_loc][l16 * 4]) =
            make_float4(ax + bx, ay + by, az + bz, aw + bw);
    }
    __syncthreads();

    // gemm: thread t -> row (t>>4), cols (t&15)*4..+3
    int col4 = (t & 15) * 4;
    int row = t >> 4;
    int nn = blockIdx.x * 16 + row;
    if (nn < N) {
        float4 acc = make_float4(0.f, 0.f, 0.f, 0.f);
        #pragma unroll
        for (int k = 0; k < D; k += 4) {
            float4 zv = *reinterpret_cast<const float4*>(&zs[row][k]);
            float4 w0 = *reinterpret_cast<const float4*>(&Wl[(k + 0) * D + col4]);
            float4 w1 = *reinterpret_cast<const float4*>(&Wl[(k + 1) * D + col4]);
            float4 w2 = *reinterpret_cast<const float4*>(&Wl[(k + 2) * D + col4]);
            float4 w3 = *reinterpret_cast<const float4*>(&Wl[(k + 3) * D + col4]);
            acc.x = fmaf(zv.x, w0.x, acc.x); acc.y = fmaf(zv.x, w0.y, acc.y);
            acc.z = fmaf(zv.x, w0.z, acc.z); acc.w = fmaf(zv.x, w0.w, acc.w);
            acc.x = fmaf(zv.y, w1.x, acc.x); acc.y = fmaf(zv.y, w1.y, acc.y);
            acc.z = fmaf(zv.y, w1.z, acc.z); acc.w = fmaf(zv.y, w1.w, acc.w);
            acc.x = fmaf(zv.z, w2.x, acc.x); acc.y = fmaf(zv.z, w2.y, acc.y);
            acc.z = fmaf(zv.z, w2.z, acc.z); acc.w = fmaf(zv.z, w2.w, acc.w);
            acc.x = fmaf(zv.w, w3.x, acc.x); acc.y = fmaf(zv.w, w3.y, acc.y);
            acc.z = fmaf(zv.w, w3.z, acc.z); acc.w = fmaf(zv.w, w3.w, acc.w);
        }
        float4 bv = *reinterpret_cast<const float4*>(&b[col4]);
        float4 r = make_float4(acc.x + bv.x, acc.y + bv.y, acc.z + bv.z, acc.w + bv.w);
        if (RELU) {
            r.x = fmaxf(r.x, 0.f); r.y = fmaxf(r.y, 0.f);
            r.z = fmaxf(r.z, 0.f); r.w = fmaxf(r.w, 0.f);
        }
        *reinterpret_cast<float4*>(&y[(size_t)nn * D + col4]) = r;
    }
}

// Dual-output variant for the final layer (mu, logvar share the aggregation).
__global__ __launch_bounds__(256) void k_fused_dual(const float* __restrict__ x,
                                                    const int* __restrict__ rp,
                                                    const int* __restrict__ packi,
                                                    const float* __restrict__ dinv,
                                                    const float* __restrict__ Wa,
                                                    const float* __restrict__ ba,
                                                    const float* __restrict__ Wb,
                                                    const float* __restrict__ bb,
                                                    float* __restrict__ ya,
                                                    float* __restrict__ yb, int N) {
    __shared__ float Wla[D * D];
    __shared__ float Wlb[D * D];
    __shared__ float zs[16][68];
    int t = threadIdx.x;

    #pragma unroll
    for (int r = 0; r < 4; ++r) {
        float4 wv = reinterpret_cast<const float4*>(Wa)[t + 256 * r];
        *reinterpret_cast<float4*>(&Wla[(t + 256 * r) * 4]) = wv;
        float4 wv2 = reinterpret_cast<const float4*>(Wb)[t + 256 * r];
        *reinterpret_cast<float4*>(&Wlb[(t + 256 * r) * 4]) = wv2;
    }

    int lane = t & 63;
    int g = lane >> 4;
    int l16 = lane & 15;
    int r_loc = (t >> 6) * 4 + g;
    int n = blockIdx.x * 16 + r_loc;
    if (n < N) {
        int s0 = rp[n], s1 = rp[n + 1];
        float dn = dinv[n];
        const float4* x4 = reinterpret_cast<const float4*>(x);
        const int4* pk = reinterpret_cast<const int4*>(packi);
        float4 sv = x4[(size_t)n * 16 + l16];
        float dnn = dn * dn;
        float ax = sv.x * dnn, ay = sv.y * dnn, az = sv.z * dnn, aw = sv.w * dnn;
        float bx = 0.f, by = 0.f, bz = 0.f, bw = 0.f;
        int e = s0;
        int4 q0, q1, q2, q3;
        if (e < s1) {
            int h = e >> 1;
            q0 = pk[h]; q1 = pk[h + 1]; q2 = pk[h + 2]; q3 = pk[h + 3];
        }
        while (e < s1) {
            float4 v0 = x4[(size_t)q0.x * 16 + l16];
            float4 v1 = x4[(size_t)q0.z * 16 + l16];
            float4 v2 = x4[(size_t)q1.x * 16 + l16];
            float4 v3 = x4[(size_t)q1.z * 16 + l16];
            float4 v4 = x4[(size_t)q2.x * 16 + l16];
            float4 v5 = x4[(size_t)q2.z * 16 + l16];
            float4 v6 = x4[(size_t)q3.x * 16 + l16];
            float4 v7 = x4[(size_t)q3.z * 16 + l16];
            float c0 = __int_as_float(q0.y) * dn, c1 = __int_as_float(q0.w) * dn;
            float c2 = __int_as_float(q1.y) * dn, c3 = __int_as_float(q1.w) * dn;
            float c4 = __int_as_float(q2.y) * dn, c5 = __int_as_float(q2.w) * dn;
            float c6 = __int_as_float(q3.y) * dn, c7 = __int_as_float(q3.w) * dn;
            e += 8;
            if (e < s1) {
                int h = e >> 1;
                q0 = pk[h]; q1 = pk[h + 1]; q2 = pk[h + 2]; q3 = pk[h + 3];
            }
            ax = fmaf(v0.x, c0, ax); ay = fmaf(v0.y, c0, ay); az = fmaf(v0.z, c0, az); aw = fmaf(v0.w, c0, aw);
            bx = fmaf(v1.x, c1, bx); by = fmaf(v1.y, c1, by); bz = fmaf(v1.z, c1, bz); bw = fmaf(v1.w, c1, bw);
            ax = fmaf(v2.x, c2, ax); ay = fmaf(v2.y, c2, ay); az = fmaf(v2.z, c2, az); aw = fmaf(v2.w, c2, aw);
            bx = fmaf(v3.x, c3, bx); by = fmaf(v3.y, c3, by); bz = fmaf(v3.z, c3, bz); bw = fmaf(v3.w, c3, bw);
            ax = fmaf(v4.x, c4, ax); ay = fmaf(v4.y, c4, ay); az = fmaf(v4.z, c4, az); aw = fmaf(v4.w, c4, aw);
            bx = fmaf(v5.x, c5, bx); by = fmaf(v5.y, c5, by); bz = fmaf(v5.z, c5, bz); bw = fmaf(v5.w, c5, bw);
            ax = fmaf(v6.x, c6, ax); ay = fmaf(v6.y, c6, ay); az = fmaf(v6.z, c6, az); aw = fmaf(v6.w, c6, aw);
            bx = fmaf(v7.x, c7, bx); by = fmaf(v7.y, c7, by); bz = fmaf(v7.z, c7, bz); bw = fmaf(v7.w, c7, bw);
        }
        *reinterpret_cast<float4*>(&zs[r_loc][l16 * 4]) =
            make_float4(ax + bx, ay + by, az + bz, aw + bw);
    }
    __syncthreads();

    int col4 = (t & 15) * 4;
    int row = t >> 4;
    int nn = blockIdx.x * 16 + row;
    if (nn < N) {
        float4 acc = make_float4(0.f, 0.f, 0.f, 0.f);
        float4 acd = make_float4(0.f, 0.f, 0.f, 0.f);
        #pragma unroll
        for (int k = 0; k < D; k += 2) {
            float z0 = zs[row][k], z1 = zs[row][k + 1];
            float4 w0 = *reinterpret_cast<const float4*>(&Wla[(k + 0) * D + col4]);
            float4 w1 = *reinterpret_cast<const float4*>(&Wla[(k + 1) * D + col4]);
            float4 u0 = *reinterpret_cast<const float4*>(&Wlb[(k + 0) * D + col4]);
            float4 u1 = *reinterpret_cast<const float4*>(&Wlb[(k + 1) * D + col4]);
            acc.x = fmaf(z0, w0.x, acc.x); acc.y = fmaf(z0, w0.y, acc.y);
            acc.z = fmaf(z0, w0.z, acc.z); acc.w = fmaf(z0, w0.w, acc.w);
            acc.x = fmaf(z1, w1.x, acc.x); acc.y = fmaf(z1, w1.y, acc.y);
            acc.z = fmaf(z1, w1.z, acc.z); acc.w = fmaf(z1, w1.w, acc.w);
            acd.x = fmaf(z0, u0.x, acd.x); acd.y = fmaf(z0, u0.y, acd.y);
            acd.z = fmaf(z0, u0.z, acd.z); acd.w = fmaf(z0, u0.w, acd.w);
            acd.x = fmaf(z1, u1.x, acd.x); acd.y = fmaf(z1, u1.y, acd.y);
            acd.z = fmaf(z1, u1.z, acd.z); acd.w = fmaf(z1, u1.w, acd.w);
        }
        float4 bav = *reinterpret_cast<const float4*>(&ba[col4]);
        float4 bbv = *reinterpret_cast<const float4*>(&bb[col4]);
        *reinterpret_cast<float4*>(&ya[(size_t)nn * D + col4]) =
            make_float4(acc.x + bav.x, acc.y + bav.y, acc.z + bav.z, acc.w + bav.w);
        *reinterpret_cast<float4*>(&yb[(size_t)nn * D + col4]) =
            make_float4(acd.x + bbv.x, acd.y + bbv.y, acd.z + bbv.z, acd.w + bbv.w);
    }
}

extern "C" void kernel_launch(void* const* d_in, const int* in_sizes, int n_in,
                              void* d_out, int out_size, void* d_ws, size_t ws_size,
                              hipStream_t stream) {
    const float* x0  = (const float*)d_in[0];
    const int*   ei  = (const int*)d_in[1];
    const float* W1  = (const float*)d_in[2];
    const float* b1  = (const float*)d_in[3];
    const float* W2  = (const float*)d_in[4];
    const float* b2  = (const float*)d_in[5];
    const float* Wsc = (const float*)d_in[6];
    const float* bs  = (const float*)d_in[7];
    const float* Wmu = (const float*)d_in[8];
    const float* bmu = (const float*)d_in[9];
    const float* Wlv = (const float*)d_in[10];
    const float* blv = (const float*)d_in[11];

    int N = in_sizes[0] / D;
    int E = in_sizes[1] / 2;
    const int* src = ei;
    const int* dst = ei + E;

    char* ws = (char*)d_ws;
    size_t off = 0;
    auto alloc = [&](size_t bytes) {
        char* p = ws + off;
        off += (bytes + 255) & ~(size_t)255;
        return p;
    };
    int*   rp   = (int*)alloc((size_t)(N + 1) * 4);
    float* dinv = (float*)alloc((size_t)N * 4);
    int NB = (N + 255) / 256;  // 196 <= 256: single-block scan2 is valid
    int* part = (int*)alloc((size_t)NB * 4);
    int* boff = (int*)alloc((size_t)NB * 4);
    int* rank = (int*)alloc((size_t)E * 4);
    int* off8 = (int*)alloc((size_t)8 * N * 4);
    // cnt8 and pack adjacent -> one contiguous zero-fill covers both
    char* zero_base = ws + off;
    int*  cnt8 = (int*)alloc((size_t)8 * N * 4);
    int2* pack = (int2*)alloc(((size_t)E + 8 * (size_t)N) * 8);  // padded CSR (x8 lists)
    size_t zero_bytes = (size_t)((char*)(pack + E + 8 * (size_t)N) - zero_base);
    int n4 = (int)((zero_bytes + 15) / 16);
    float* h1 = (float*)alloc((size_t)N * D * 4);
    float* h2 = (float*)alloc((size_t)N * D * 4);

    float* mu = (float*)d_out;
    float* lv = (float*)d_out + (size_t)N * D;

    int EB = (E + 255) / 256;
    k_zero4<<<(n4 + 255) / 256, 256, 0, stream>>>((float4*)zero_base, n4);
    k_deg  <<<EB, 256, 0, stream>>>(dst, cnt8, rank, N, E);
    k_scan1<<<NB, 256, 0, stream>>>(cnt8, part, N);
    k_scan2<<<1, 256, 0, stream>>>(part, boff, NB);
    k_scan3<<<NB, 256, 0, stream>>>(cnt8, boff, rp, off8, dinv, N);
    k_fill <<<EB, 256, 0, stream>>>(src, dst, rank, off8, dinv, pack, N, E);

    int FB = (N + 15) / 16;   // 16 nodes per 256-thread block
    // agg(x)@W == agg(x@W) by linearity; mu/logvar share the last aggregation.
    k_fused<0><<<FB, 256, 0, stream>>>(x0, rp, (const int*)pack, dinv, W1, b1, h1, N);
    k_fused<0><<<FB, 256, 0, stream>>>(h1, rp, (const int*)pack, dinv, W2, b2, h2, N);
    k_fused<1><<<FB, 256, 0, stream>>>(h2, rp, (const int*)pack, dinv, Wsc, bs, h1, N);
    k_fused_dual<<<FB, 256, 0, stream>>>(h1, rp, (const int*)pack, dinv,
                                         Wmu, bmu, Wlv, blv, mu, lv, N);
}